// Round 6
// baseline (417.754 us; speedup 1.0000x reference)
//
#include <hip/hip_runtime.h>
#include <hip/hip_bf16.h>
#include <stdint.h>

// GraphAttentionLayer: out = softmax(h A h^T, axis=1) @ h,  h = X W^T + b
// N=8192, IN_F=256, D=OUT_F=128. adjacency_matrix (d_in[0]) is UNUSED.
//
// v10 = v9 (harness-verified, 409.1 us) + two minimal deltas:
//  - prep: grid 1024 x 8 rows (was 512 x 16) -> 4 blocks/CU, 4 waves/SIMD.
//    prep is VALU/latency-bound; more TLP. Same arithmetic.
//  - flash QK loop interchange: t-outer (was jt-outer) -> 8 independent
//    accumulator chains per t-step instead of 2 chains of depth 12.
//    Identical accumulation order per st[it][jt] (bitwise-same result).
//  flash sync structure + combine byte-identical to v9.
//
// ws layout (bytes):            size
//   h_hi  [128 tiles][64][128] bf16 (swizzled K image)   2 MB @ 0
//   h_lo  same                                           2 MB @ 2 MB
//   q_hi  [8192][128] bf16 (plain)                       2 MB @ 4 MB
//   q_lo  [8192][128] bf16 (plain)                       2 MB @ 6 MB
//   htp   [128 tiles][128 d][64 j] bf16 (perm+swz V img) 2 MB @ 8 MB
//   opart [8][8192][128] bf16 (normalized O/l)          16 MB @ 10 MB
//   mpart [8][8192] f32                               256 KB @ 26 MB
//   lpart [8][8192] f32                               256 KB @ 26 MB+256 KB

#define NN 8192
#define INF_ 256
#define D 128
#define BQ 128          // Q rows per block (4 waves x 32)
#define BK 64
#define KSPLIT 8
#define KSEG (NN / KSPLIT)
#define NTILE (KSEG / BK)
#define L2E 1.44269504088896340736f
#define RESCALE_THR 8.0f

typedef __attribute__((ext_vector_type(8))) short bf16x8;
typedef __attribute__((ext_vector_type(8))) unsigned short u16x8;
typedef __attribute__((ext_vector_type(4))) float f32x4;

// async 16B global->LDS (gfx950: global_load_lds_dwordx4).
// LDS dest = wave-uniform base + lane*16; both pointers via integer casts.
__device__ __forceinline__ void gld16(const __hip_bfloat16* g, __hip_bfloat16* l) {
    __builtin_amdgcn_global_load_lds(
        (const __attribute__((address_space(1))) unsigned int*)(unsigned long long)(uintptr_t)g,
        (__attribute__((address_space(3))) unsigned int*)(unsigned long long)(uintptr_t)l,
        16, 0, 0);
}

// K-image element offset for global row `grow`, col c (tile-major):
// tile = grow>>6; within: row*128 + (chunk ^ (row&15))*8 + (c&7)
__device__ __forceinline__ size_t k_img(int grow, int c) {
    const int row = grow & 63;
    return (size_t)(grow >> 6) * 8192 + row * 128 + (((c >> 3) ^ (row & 15)) * 8) + (c & 7);
}

// V-image element offset for global node j, dim c:
// pv kslot perm within 64-block, then chunk swizzle by (c&7)
__device__ __forceinline__ size_t v_img(int j, int c) {
    const int jj = j & 63;
    const int jt = (jj >> 4) & 3, q = (jj >> 2) & 3, r = jj & 3;
    const int jp = (jt >> 1) * 32 + q * 8 + (jt & 1) * 4 + r;
    return (size_t)(j >> 6) * 8192 + c * 64 + (((jp >> 3) ^ (c & 7)) * 8) + (jp & 7);
}

// ---------------------------------------------------------------- prep ----
// h = X@W^T + b (fp32), Q = h@A (fp32); emit K images (hi/lo), V image, Q splits.
// 1024 blocks x 8 rows: 4 blocks/CU -> 4 waves/SIMD (v9 had 2).
__global__ __launch_bounds__(256) void prep_kernel(
    const float* __restrict__ X, const float* __restrict__ W,
    const float* __restrict__ bias, const float* __restrict__ A,
    __hip_bfloat16* __restrict__ h_hi, __hip_bfloat16* __restrict__ h_lo,
    __hip_bfloat16* __restrict__ q_hi, __hip_bfloat16* __restrict__ q_lo,
    __hip_bfloat16* __restrict__ htp)
{
    __shared__ float xs[8][INF_];    // 8 KB
    __shared__ float hs[8][D];       // 4 KB
    const int tid  = threadIdx.x;
    const int row0 = blockIdx.x * 8;

    {   // stage X tile (8x256 f32) coalesced: 512 f32x4, 2 per thread
        const f32x4* Xv = (const f32x4*)(X + (size_t)row0 * INF_);
        f32x4* xsv = (f32x4*)&xs[0][0];
        #pragma unroll
        for (int i = 0; i < 2; ++i) xsv[tid + i*256] = Xv[tid + i*256];
    }
    __syncthreads();

    const int c  = tid & 127;   // output column
    const int rh = tid >> 7;    // row half (0/1) -> rows rh*4..rh*4+3

    // ---- h = X W^T + b ----
    float acc[4];
    #pragma unroll
    for (int r = 0; r < 4; ++r) acc[r] = 0.f;
    const f32x4* Wv = (const f32x4*)(W + (size_t)c * INF_);
    for (int k4 = 0; k4 < INF_/4; ++k4) {
        f32x4 w4 = Wv[k4];
        #pragma unroll
        for (int r = 0; r < 4; ++r) {
            f32x4 x4 = ((const f32x4*)&xs[rh*4 + r][0])[k4];  // LDS broadcast
            acc[r] += x4[0]*w4[0] + x4[1]*w4[1] + x4[2]*w4[2] + x4[3]*w4[3];
        }
    }
    const float bc = bias[c];
    #pragma unroll
    for (int r = 0; r < 4; ++r) {
        const int row = rh*4 + r;
        const int grow = row0 + row;
        const float hv = acc[r] + bc;
        hs[row][c] = hv;
        const __hip_bfloat16 hi = __float2bfloat16(hv);
        const float lo = hv - __bfloat162float(hi);
        h_hi[k_img(grow, c)] = hi;
        h_lo[k_img(grow, c)] = __float2bfloat16(lo);
        htp [v_img(grow, c)] = hi;
    }
    __syncthreads();

    // ---- Q = h @ A ----
    float acc2[4];
    #pragma unroll
    for (int r = 0; r < 4; ++r) acc2[r] = 0.f;
    for (int d4 = 0; d4 < D/4; ++d4) {
        f32x4 hv4[4];
        #pragma unroll
        for (int r = 0; r < 4; ++r) hv4[r] = ((const f32x4*)&hs[rh*4 + r][0])[d4];
        #pragma unroll
        for (int dd = 0; dd < 4; ++dd) {
            const float a = A[(size_t)(d4*4 + dd)*D + c];   // coalesced over c
            #pragma unroll
            for (int r = 0; r < 4; ++r) acc2[r] += hv4[r][dd] * a;
        }
    }
    #pragma unroll
    for (int r = 0; r < 4; ++r) {
        const int row = rh*4 + r;
        const float tv = acc2[r];
        const __hip_bfloat16 hi = __float2bfloat16(tv);
        const float lo = tv - __bfloat162float(hi);
        q_hi[(size_t)(row0+row)*D + c] = hi;
        q_lo[(size_t)(row0+row)*D + c] = __float2bfloat16(lo);
    }
}

// --------------------------------------------------------------- flash ----
// flat grid 512 blocks, 256 threads (4 waves). split = bid&7 (XCD-resident
// K-stream), qblk = bid>>3. Wave w owns Q rows q0 + w*32 + it*16 + l16.
//
// MFMA operand facts (verified rounds 1-4):
//   A-frag 16x16x32: lane(l16,quad) holds A[m=l16][k=quad*8+0..7]
//   B-frag:          lane(l16,quad) holds B[n=l16][k=quad*8+0..7]
//   C:               reg r holds      C[m=quad*4+r][n=l16]
//
// Schedule per tile (2-phase, one-tile-ahead staging):
//   __syncthreads()              // drains K[t],V[t] DMAs (only VMEM in flight)
//   QK MFMAs (read khi/klo)      // setprio 1; t-outer: 8 indep acc chains
//   __syncthreads()              // all waves done reading khi/klo (cheap: no VMEM)
//   if (t+1<NTILE) issue K[t+1] -> khi/klo, V[t+1] -> vt[(t+1)&1]
//   softmax (defer-max) ; PV MFMAs (read vt[t&1], setprio 1)
//   // DMA latency hides under softmax+PV; next-top sync drains it.
__global__ __launch_bounds__(256, 2) void flash_kernel(
    const __hip_bfloat16* __restrict__ q_hi, const __hip_bfloat16* __restrict__ q_lo,
    const __hip_bfloat16* __restrict__ k_hi, const __hip_bfloat16* __restrict__ k_lo,
    const __hip_bfloat16* __restrict__ htp,
    __hip_bfloat16* __restrict__ opart, float* __restrict__ mpart,
    float* __restrict__ lpart)
{
    __shared__ __hip_bfloat16 khi[BK*128];     // 16 KB  (swizzled image)
    __shared__ __hip_bfloat16 klo[BK*128];     // 16 KB
    __shared__ __hip_bfloat16 vt [2*D*64];     // 32 KB  (double-buffered)

    const int tid  = threadIdx.x;
    const int wave = tid >> 6;
    const int lane = tid & 63;
    const int l16  = lane & 15;
    const int quad = lane >> 4;
    const int bid   = blockIdx.x;
    const int split = bid & 7;               // same-XCD blocks share a split
    const int q0    = (bid >> 3) * BQ;
    const int tbase = split * NTILE;         // 64-row tile index base

    // Q fragments (B-operand; n=l16 selects the Q row) for both i-tiles
    bf16x8 bqh[2][4], bql[2][4];
    #pragma unroll
    for (int it = 0; it < 2; ++it) {
        const size_t qrow = (size_t)q0 + wave*32 + it*16 + l16;
        const __hip_bfloat16* qhp = q_hi + qrow*D;
        const __hip_bfloat16* qlp = q_lo + qrow*D;
        #pragma unroll
        for (int t = 0; t < 4; ++t) {
            bqh[it][t] = *(const bf16x8*)(qhp + t*32 + quad*8);
            bql[it][t] = *(const bf16x8*)(qlp + t*32 + quad*8);
        }
    }

    // prologue: stage tile 0 (K -> khi/klo, V -> buffer 0)
    {
        const size_t tb = (size_t)tbase * 8192;
        #pragma unroll
        for (int i = 0; i < 4; ++i) {
            const int cb = (i*4 + wave) * 64;              // wave-uniform chunk base
            const size_t ge = tb + (size_t)(cb + lane) * 8;
            gld16(k_hi + ge, &khi[cb*8]);
            gld16(k_lo + ge, &klo[cb*8]);
            gld16(htp  + ge, &vt [cb*8]);
        }
    }

    f32x4 oacc[2][8];
    #pragma unroll
    for (int it = 0; it < 2; ++it)
        #pragma unroll
        for (int i = 0; i < 8; ++i) oacc[it][i] = (f32x4){0.f, 0.f, 0.f, 0.f};
    float mi[2] = {-1e30f, -1e30f}, li[2] = {0.f, 0.f};

    for (int tile = 0; tile < NTILE; ++tile) {
        __syncthreads();   // drains tile's K/V DMAs (the only VMEM in flight) + converge

        // ---- S^T strips: st[it][jt] rows j=jt*16+quad*4+r, col i=l16
        // t-outer: per t-step, 8 independent (it,jt) accumulator chains.
        f32x4 st[2][4];
        __builtin_amdgcn_s_setprio(1);
        #pragma unroll
        for (int t = 0; t < 4; ++t) {
            #pragma unroll
            for (int jt = 0; jt < 4; ++jt) {
                const int ko = (jt*16 + l16)*128 + (((t*4 + quad) ^ l16) * 8);
                const bf16x8 ah = *(const bf16x8*)(&khi[ko]);
                const bf16x8 al = *(const bf16x8*)(&klo[ko]);
                #pragma unroll
                for (int it = 0; it < 2; ++it) {
                    f32x4 acc = (t == 0) ? (f32x4){0.f,0.f,0.f,0.f} : st[it][jt];
                    acc = __builtin_amdgcn_mfma_f32_16x16x32_bf16(ah, bql[it][t], acc, 0, 0, 0);
                    acc = __builtin_amdgcn_mfma_f32_16x16x32_bf16(al, bqh[it][t], acc, 0, 0, 0);
                    acc = __builtin_amdgcn_mfma_f32_16x16x32_bf16(ah, bqh[it][t], acc, 0, 0, 0);
                    st[it][jt] = acc;
                }
            }
        }
        __builtin_amdgcn_s_setprio(0);

        __syncthreads();   // all waves done reading khi/klo; no VMEM outstanding (cheap)

        if (tile + 1 < NTILE) {
            // one-tile-ahead staging; latency hides under softmax + PV below.
            const size_t tb = (size_t)(tbase + tile + 1) * 8192;
            const int vb = ((tile + 1) & 1) * (D*64);
            #pragma unroll
            for (int i = 0; i < 4; ++i) {
                const int cb = (i*4 + wave) * 64;
                const size_t ge = tb + (size_t)(cb + lane) * 8;
                gld16(k_hi + ge, &khi[cb*8]);
                gld16(k_lo + ge, &klo[cb*8]);
                gld16(htp  + ge, &vt [vb + cb*8]);
            }
        }
        __builtin_amdgcn_sched_barrier(0);   // pin DMA issues before softmax (compile-time)

        // ---- online softmax (lane owns row i = it*16 + l16), deferred max
        bf16x8 pb[2][2];
        #pragma unroll
        for (int it = 0; it < 2; ++it) {
            float vmax = st[it][0][0];
            #pragma unroll
            for (int jt = 0; jt < 4; ++jt)
                #pragma unroll
                for (int r = 0; r < 4; ++r) vmax = fmaxf(vmax, st[it][jt][r]);
            vmax = fmaxf(vmax, __shfl_xor(vmax, 16, 64));
            vmax = fmaxf(vmax, __shfl_xor(vmax, 32, 64));
            // T13: only rescale when some row's max grew past the threshold.
            // Keeping stale mi is exact: li accumulates exp(S - mi_stored) and
            // combine reweights by l_s * 2^(m_s - m); P <= e^8 fits bf16 with
            // unchanged relative error.
            if (!__all(vmax <= mi[it] + RESCALE_THR)) {
                const float mnew  = fmaxf(mi[it], vmax);
                const float alpha = exp2f((mi[it] - mnew) * L2E);
                mi[it] = mnew;
                li[it] *= alpha;
                #pragma unroll
                for (int r = 0; r < 4; ++r) {     // C rows are quad*4+r
                    const float ar = __shfl(alpha, quad*4 + r, 64);
                    #pragma unroll
                    for (int dt = 0; dt < 8; ++dt) oacc[it][dt][r] *= ar;
                }
            }
            const float mcur = mi[it];
            float sum = 0.f;
            #pragma unroll
            for (int jt = 0; jt < 4; ++jt)
                #pragma unroll
                for (int r = 0; r < 4; ++r) {
                    const float pv = exp2f((st[it][jt][r] - mcur) * L2E);
                    st[it][jt][r] = pv;
                    sum += pv;
                }
            sum += __shfl_xor(sum, 16, 64);
            sum += __shfl_xor(sum, 32, 64);
            li[it] += sum;
            // pack P as PV A-operand (kslot relabeling: jt-pair per frag)
            #pragma unroll
            for (int jp = 0; jp < 2; ++jp) {
                bf16x8 f;
                #pragma unroll
                for (int r = 0; r < 4; ++r) {
                    f[r]     = __bfloat16_as_short(__float2bfloat16(st[it][2*jp  ][r]));
                    f[r + 4] = __bfloat16_as_short(__float2bfloat16(st[it][2*jp+1][r]));
                }
                pb[it][jp] = f;
            }
        }

        // ---- PV: O[m=i][n=d]; B-frag = one b128 from swizzled V image.
        // Reads vt[tile&1]; in-flight DMA targets vt[(tile+1)&1] — disjoint.
        const int vr = (tile & 1) * (D*64);
        __builtin_amdgcn_s_setprio(1);
        #pragma unroll
        for (int dt = 0; dt < 8; ++dt) {
            const int vo = vr + (dt*16 + l16)*64;
            #pragma unroll
            for (int jp = 0; jp < 2; ++jp) {
                const bf16x8 bv = *(const bf16x8*)(&vt[vo + (((jp*4 + quad) ^ (l16 & 7)) * 8)]);
                #pragma unroll
                for (int it = 0; it < 2; ++it)
                    oacc[it][dt] = __builtin_amdgcn_mfma_f32_16x16x32_bf16(
                        pb[it][jp], bv, oacc[it][dt], 0, 0, 0);
            }
        }
        __builtin_amdgcn_s_setprio(0);
    }

    // ---- epilogue: NORMALIZED bf16 split-K partials (O/l), plus m & l
    __hip_bfloat16* op = opart + ((size_t)split * NN + q0 + wave*32) * D;
    #pragma unroll
    for (int it = 0; it < 2; ++it) {
        const float linv = 1.f / li[it];     // lane l16 holds row it*16+l16
        #pragma unroll
        for (int r = 0; r < 4; ++r) {
            const int m = it*16 + quad*4 + r;
            const float lr = __shfl(linv, quad*4 + r, 64);
            #pragma unroll
            for (int dt = 0; dt < 8; ++dt)
                op[(size_t)m*D + dt*16 + l16] = __float2bfloat16(oacc[it][dt][r] * lr);
        }
        if (quad == 0) {
            mpart[(size_t)split*NN + q0 + wave*32 + it*16 + l16] = mi[it];
            lpart[(size_t)split*NN + q0 + wave*32 + it*16 + l16] = li[it];
        }
    }
}

// ------------------------------------------------------------- combine ----
// out[q][d] = sum_s g_s * O'_s[q][d] / sum_s g_s,  g_s = l_s * 2^(m_s - m).
// One thread per 8 contiguous d of one q: bf16x8 loads, two f32x4 stores.
__global__ __launch_bounds__(256) void combine_kernel(
    const __hip_bfloat16* __restrict__ opart, const float* __restrict__ mpart,
    const float* __restrict__ lpart, float* __restrict__ out)
{
    const int idx = blockIdx.x * 256 + threadIdx.x;   // over 8192*16
    const int q  = idx >> 4;
    const int d8 = (idx & 15) * 8;
    float m = -1e30f;
    #pragma unroll
    for (int s = 0; s < KSPLIT; ++s) m = fmaxf(m, mpart[(size_t)s*NN + q]);
    float z = 0.f, o[8];
    #pragma unroll
    for (int e = 0; e < 8; ++e) o[e] = 0.f;
    #pragma unroll
    for (int s = 0; s < KSPLIT; ++s) {
        const float g = lpart[(size_t)s*NN + q] * exp2f((mpart[(size_t)s*NN + q] - m) * L2E);
        z += g;
        const u16x8 v = *(const u16x8*)(opart + ((size_t)s*NN + q)*D + d8);
        #pragma unroll
        for (int e = 0; e < 8; ++e)
            o[e] += g * __uint_as_float((unsigned)v[e] << 16);
    }
    const float zinv = 1.f / z;
    f32x4 lo, hi;
    #pragma unroll
    for (int e = 0; e < 4; ++e) { lo[e] = o[e] * zinv; hi[e] = o[e+4] * zinv; }
    *(f32x4*)(out + (size_t)q*D + d8)     = lo;
    *(f32x4*)(out + (size_t)q*D + d8 + 4) = hi;
}

// ---------------------------------------------------------------- launch --
extern "C" void kernel_launch(void* const* d_in, const int* in_sizes, int n_in,
                              void* d_out, int out_size, void* d_ws, size_t ws_size,
                              hipStream_t stream)
{
    // setup_inputs order: adjacency(0, UNUSED), node_features(1), W(2), b(3), attn_weights(4)
    const float* X = (const float*)d_in[1];
    const float* W = (const float*)d_in[2];
    const float* b = (const float*)d_in[3];
    const float* A = (const float*)d_in[4];
    float* out = (float*)d_out;

    char* ws = (char*)d_ws;
    __hip_bfloat16* h_hi = (__hip_bfloat16*)(ws);
    __hip_bfloat16* h_lo = (__hip_bfloat16*)(ws + (size_t)(2u  << 20));
    __hip_bfloat16* q_hi = (__hip_bfloat16*)(ws + (size_t)(4u  << 20));
    __hip_bfloat16* q_lo = (__hip_bfloat16*)(ws + (size_t)(6u  << 20));
    __hip_bfloat16* htp  = (__hip_bfloat16*)(ws + (size_t)(8u  << 20));
    __hip_bfloat16* opart = (__hip_bfloat16*)(ws + (size_t)(10u << 20));
    float* mpart = (float*)(ws + (size_t)(26u << 20));
    float* lpart = (float*)(ws + (size_t)(26u << 20) + (256u << 10));

    prep_kernel<<<NN/8, 256, 0, stream>>>(X, W, b, A, h_hi, h_lo, q_hi, q_lo, htp);
    flash_kernel<<<(NN/BQ) * KSPLIT, 256, 0, stream>>>(
        q_hi, q_lo, h_hi, h_lo, htp, opart, mpart, lpart);
    combine_kernel<<<(NN*16)/256, 256, 0, stream>>>(opart, mpart, lpart, out);
}

// Round 7
// 409.019 us; speedup vs baseline: 1.0214x; 1.0214x over previous
//
#include <hip/hip_runtime.h>
#include <hip/hip_bf16.h>
#include <stdint.h>

// GraphAttentionLayer: out = softmax(h A h^T, axis=1) @ h,  h = X W^T + b
// N=8192, IN_F=256, D=OUT_F=128. adjacency_matrix (d_in[0]) is UNUSED.
//
// v11 = exact revert to v9 (harness-verified best, 409.1 us).
// v10's two deltas (prep 1024x8, QK t-outer interchange) regressed +8.7 us:
//  - prep 1024x8 doubled W/A re-read traffic (each block streams full W) and
//    halved the r-unroll amortization -> W-bound.
//  - QK t-outer widened register lifetimes at the kernel's hottest point.
// Both reverted. prep 512x16 (2 blocks/CU), flash jt-outer QK, 2-phase
// one-tile-ahead staging, V double-buffer, defer-max, setprio, standalone
// combine.
//
// ws layout (bytes):            size
//   h_hi  [128 tiles][64][128] bf16 (swizzled K image)   2 MB @ 0
//   h_lo  same                                           2 MB @ 2 MB
//   q_hi  [8192][128] bf16 (plain)                       2 MB @ 4 MB
//   q_lo  [8192][128] bf16 (plain)                       2 MB @ 6 MB
//   htp   [128 tiles][128 d][64 j] bf16 (perm+swz V img) 2 MB @ 8 MB
//   opart [8][8192][128] bf16 (normalized O/l)          16 MB @ 10 MB
//   mpart [8][8192] f32                               256 KB @ 26 MB
//   lpart [8][8192] f32                               256 KB @ 26 MB+256 KB

#define NN 8192
#define INF_ 256
#define D 128
#define BQ 128          // Q rows per block (4 waves x 32)
#define BK 64
#define KSPLIT 8
#define KSEG (NN / KSPLIT)
#define NTILE (KSEG / BK)
#define L2E 1.44269504088896340736f
#define RESCALE_THR 8.0f

typedef __attribute__((ext_vector_type(8))) short bf16x8;
typedef __attribute__((ext_vector_type(8))) unsigned short u16x8;
typedef __attribute__((ext_vector_type(4))) float f32x4;

// async 16B global->LDS (gfx950: global_load_lds_dwordx4).
// LDS dest = wave-uniform base + lane*16; both pointers via integer casts.
__device__ __forceinline__ void gld16(const __hip_bfloat16* g, __hip_bfloat16* l) {
    __builtin_amdgcn_global_load_lds(
        (const __attribute__((address_space(1))) unsigned int*)(unsigned long long)(uintptr_t)g,
        (__attribute__((address_space(3))) unsigned int*)(unsigned long long)(uintptr_t)l,
        16, 0, 0);
}

// K-image element offset for global row `grow`, col c (tile-major):
// tile = grow>>6; within: row*128 + (chunk ^ (row&15))*8 + (c&7)
__device__ __forceinline__ size_t k_img(int grow, int c) {
    const int row = grow & 63;
    return (size_t)(grow >> 6) * 8192 + row * 128 + (((c >> 3) ^ (row & 15)) * 8) + (c & 7);
}

// V-image element offset for global node j, dim c:
// pv kslot perm within 64-block, then chunk swizzle by (c&7)
__device__ __forceinline__ size_t v_img(int j, int c) {
    const int jj = j & 63;
    const int jt = (jj >> 4) & 3, q = (jj >> 2) & 3, r = jj & 3;
    const int jp = (jt >> 1) * 32 + q * 8 + (jt & 1) * 4 + r;
    return (size_t)(j >> 6) * 8192 + c * 64 + (((jp >> 3) ^ (c & 7)) * 8) + (jp & 7);
}

// ---------------------------------------------------------------- prep ----
// h = X@W^T + b (fp32), Q = h@A (fp32); emit K images (hi/lo), V image, Q splits.
// 512 blocks x 16 rows: 2 blocks/CU -> 2 waves/SIMD.
__global__ __launch_bounds__(256) void prep_kernel(
    const float* __restrict__ X, const float* __restrict__ W,
    const float* __restrict__ bias, const float* __restrict__ A,
    __hip_bfloat16* __restrict__ h_hi, __hip_bfloat16* __restrict__ h_lo,
    __hip_bfloat16* __restrict__ q_hi, __hip_bfloat16* __restrict__ q_lo,
    __hip_bfloat16* __restrict__ htp)
{
    __shared__ float xs[16][INF_];   // 16 KB
    __shared__ float hs[16][D];      //  8 KB
    const int tid  = threadIdx.x;
    const int row0 = blockIdx.x * 16;

    {   // stage X tile (16x256 f32) coalesced: 1024 f32x4, 4 per thread
        const f32x4* Xv = (const f32x4*)(X + (size_t)row0 * INF_);
        f32x4* xsv = (f32x4*)&xs[0][0];
        #pragma unroll
        for (int i = 0; i < 4; ++i) xsv[tid + i*256] = Xv[tid + i*256];
    }
    __syncthreads();

    const int c  = tid & 127;   // output column
    const int rh = tid >> 7;    // row half (0/1) -> rows rh*8..rh*8+7

    // ---- h = X W^T + b ----
    float acc[8];
    #pragma unroll
    for (int r = 0; r < 8; ++r) acc[r] = 0.f;
    const f32x4* Wv = (const f32x4*)(W + (size_t)c * INF_);
    for (int k4 = 0; k4 < INF_/4; ++k4) {
        f32x4 w4 = Wv[k4];
        #pragma unroll
        for (int r = 0; r < 8; ++r) {
            f32x4 x4 = ((const f32x4*)&xs[rh*8 + r][0])[k4];  // LDS broadcast
            acc[r] += x4[0]*w4[0] + x4[1]*w4[1] + x4[2]*w4[2] + x4[3]*w4[3];
        }
    }
    const float bc = bias[c];
    #pragma unroll
    for (int r = 0; r < 8; ++r) {
        const int row = rh*8 + r;
        const int grow = row0 + row;
        const float hv = acc[r] + bc;
        hs[row][c] = hv;
        const __hip_bfloat16 hi = __float2bfloat16(hv);
        const float lo = hv - __bfloat162float(hi);
        h_hi[k_img(grow, c)] = hi;
        h_lo[k_img(grow, c)] = __float2bfloat16(lo);
        htp [v_img(grow, c)] = hi;
    }
    __syncthreads();

    // ---- Q = h @ A ----
    float acc2[8];
    #pragma unroll
    for (int r = 0; r < 8; ++r) acc2[r] = 0.f;
    for (int d4 = 0; d4 < D/4; ++d4) {
        f32x4 hv4[8];
        #pragma unroll
        for (int r = 0; r < 8; ++r) hv4[r] = ((const f32x4*)&hs[rh*8 + r][0])[d4];
        #pragma unroll
        for (int dd = 0; dd < 4; ++dd) {
            const float a = A[(size_t)(d4*4 + dd)*D + c];   // coalesced over c
            #pragma unroll
            for (int r = 0; r < 8; ++r) acc2[r] += hv4[r][dd] * a;
        }
    }
    #pragma unroll
    for (int r = 0; r < 8; ++r) {
        const int row = rh*8 + r;
        const float tv = acc2[r];
        const __hip_bfloat16 hi = __float2bfloat16(tv);
        const float lo = tv - __bfloat162float(hi);
        q_hi[(size_t)(row0+row)*D + c] = hi;
        q_lo[(size_t)(row0+row)*D + c] = __float2bfloat16(lo);
    }
}

// --------------------------------------------------------------- flash ----
// flat grid 512 blocks, 256 threads (4 waves). split = bid&7 (XCD-resident
// K-stream), qblk = bid>>3. Wave w owns Q rows q0 + w*32 + it*16 + l16.
//
// MFMA operand facts (verified rounds 1-4):
//   A-frag 16x16x32: lane(l16,quad) holds A[m=l16][k=quad*8+0..7]
//   B-frag:          lane(l16,quad) holds B[n=l16][k=quad*8+0..7]
//   C:               reg r holds      C[m=quad*4+r][n=l16]
//
// Schedule per tile (2-phase, one-tile-ahead staging):
//   __syncthreads()              // drains K[t],V[t] DMAs (only VMEM in flight)
//   QK MFMAs (read khi/klo)      // setprio 1
//   __syncthreads()              // all waves done reading khi/klo (cheap: no VMEM)
//   if (t+1<NTILE) issue K[t+1] -> khi/klo, V[t+1] -> vt[(t+1)&1]
//   softmax (defer-max) ; PV MFMAs (read vt[t&1], setprio 1)
//   // DMA latency hides under softmax+PV; next-top sync drains it.
__global__ __launch_bounds__(256, 2) void flash_kernel(
    const __hip_bfloat16* __restrict__ q_hi, const __hip_bfloat16* __restrict__ q_lo,
    const __hip_bfloat16* __restrict__ k_hi, const __hip_bfloat16* __restrict__ k_lo,
    const __hip_bfloat16* __restrict__ htp,
    __hip_bfloat16* __restrict__ opart, float* __restrict__ mpart,
    float* __restrict__ lpart)
{
    __shared__ __hip_bfloat16 khi[BK*128];     // 16 KB  (swizzled image)
    __shared__ __hip_bfloat16 klo[BK*128];     // 16 KB
    __shared__ __hip_bfloat16 vt [2*D*64];     // 32 KB  (double-buffered)

    const int tid  = threadIdx.x;
    const int wave = tid >> 6;
    const int lane = tid & 63;
    const int l16  = lane & 15;
    const int quad = lane >> 4;
    const int bid   = blockIdx.x;
    const int split = bid & 7;               // same-XCD blocks share a split
    const int q0    = (bid >> 3) * BQ;
    const int tbase = split * NTILE;         // 64-row tile index base

    // Q fragments (B-operand; n=l16 selects the Q row) for both i-tiles
    bf16x8 bqh[2][4], bql[2][4];
    #pragma unroll
    for (int it = 0; it < 2; ++it) {
        const size_t qrow = (size_t)q0 + wave*32 + it*16 + l16;
        const __hip_bfloat16* qhp = q_hi + qrow*D;
        const __hip_bfloat16* qlp = q_lo + qrow*D;
        #pragma unroll
        for (int t = 0; t < 4; ++t) {
            bqh[it][t] = *(const bf16x8*)(qhp + t*32 + quad*8);
            bql[it][t] = *(const bf16x8*)(qlp + t*32 + quad*8);
        }
    }

    // prologue: stage tile 0 (K -> khi/klo, V -> buffer 0)
    {
        const size_t tb = (size_t)tbase * 8192;
        #pragma unroll
        for (int i = 0; i < 4; ++i) {
            const int cb = (i*4 + wave) * 64;              // wave-uniform chunk base
            const size_t ge = tb + (size_t)(cb + lane) * 8;
            gld16(k_hi + ge, &khi[cb*8]);
            gld16(k_lo + ge, &klo[cb*8]);
            gld16(htp  + ge, &vt [cb*8]);
        }
    }

    f32x4 oacc[2][8];
    #pragma unroll
    for (int it = 0; it < 2; ++it)
        #pragma unroll
        for (int i = 0; i < 8; ++i) oacc[it][i] = (f32x4){0.f, 0.f, 0.f, 0.f};
    float mi[2] = {-1e30f, -1e30f}, li[2] = {0.f, 0.f};

    for (int tile = 0; tile < NTILE; ++tile) {
        __syncthreads();   // drains tile's K/V DMAs (the only VMEM in flight) + converge

        // ---- S^T strips: st[it][jt] rows j=jt*16+quad*4+r, col i=l16
        f32x4 st[2][4];
        __builtin_amdgcn_s_setprio(1);
        #pragma unroll
        for (int jt = 0; jt < 4; ++jt) {
            #pragma unroll
            for (int t = 0; t < 4; ++t) {
                const int ko = (jt*16 + l16)*128 + (((t*4 + quad) ^ l16) * 8);
                const bf16x8 ah = *(const bf16x8*)(&khi[ko]);
                const bf16x8 al = *(const bf16x8*)(&klo[ko]);
                #pragma unroll
                for (int it = 0; it < 2; ++it) {
                    f32x4 acc = (t == 0) ? (f32x4){0.f,0.f,0.f,0.f} : st[it][jt];
                    acc = __builtin_amdgcn_mfma_f32_16x16x32_bf16(ah, bql[it][t], acc, 0, 0, 0);
                    acc = __builtin_amdgcn_mfma_f32_16x16x32_bf16(al, bqh[it][t], acc, 0, 0, 0);
                    acc = __builtin_amdgcn_mfma_f32_16x16x32_bf16(ah, bqh[it][t], acc, 0, 0, 0);
                    st[it][jt] = acc;
                }
            }
        }
        __builtin_amdgcn_s_setprio(0);

        __syncthreads();   // all waves done reading khi/klo; no VMEM outstanding (cheap)

        if (tile + 1 < NTILE) {
            // one-tile-ahead staging; latency hides under softmax + PV below.
            const size_t tb = (size_t)(tbase + tile + 1) * 8192;
            const int vb = ((tile + 1) & 1) * (D*64);
            #pragma unroll
            for (int i = 0; i < 4; ++i) {
                const int cb = (i*4 + wave) * 64;
                const size_t ge = tb + (size_t)(cb + lane) * 8;
                gld16(k_hi + ge, &khi[cb*8]);
                gld16(k_lo + ge, &klo[cb*8]);
                gld16(htp  + ge, &vt [vb + cb*8]);
            }
        }
        __builtin_amdgcn_sched_barrier(0);   // pin DMA issues before softmax (compile-time)

        // ---- online softmax (lane owns row i = it*16 + l16), deferred max
        bf16x8 pb[2][2];
        #pragma unroll
        for (int it = 0; it < 2; ++it) {
            float vmax = st[it][0][0];
            #pragma unroll
            for (int jt = 0; jt < 4; ++jt)
                #pragma unroll
                for (int r = 0; r < 4; ++r) vmax = fmaxf(vmax, st[it][jt][r]);
            vmax = fmaxf(vmax, __shfl_xor(vmax, 16, 64));
            vmax = fmaxf(vmax, __shfl_xor(vmax, 32, 64));
            // T13: only rescale when some row's max grew past the threshold.
            // Keeping stale mi is exact: li accumulates exp(S - mi_stored) and
            // combine reweights by l_s * 2^(m_s - m); P <= e^8 fits bf16 with
            // unchanged relative error.
            if (!__all(vmax <= mi[it] + RESCALE_THR)) {
                const float mnew  = fmaxf(mi[it], vmax);
                const float alpha = exp2f((mi[it] - mnew) * L2E);
                mi[it] = mnew;
                li[it] *= alpha;
                #pragma unroll
                for (int r = 0; r < 4; ++r) {     // C rows are quad*4+r
                    const float ar = __shfl(alpha, quad*4 + r, 64);
                    #pragma unroll
                    for (int dt = 0; dt < 8; ++dt) oacc[it][dt][r] *= ar;
                }
            }
            const float mcur = mi[it];
            float sum = 0.f;
            #pragma unroll
            for (int jt = 0; jt < 4; ++jt)
                #pragma unroll
                for (int r = 0; r < 4; ++r) {
                    const float pv = exp2f((st[it][jt][r] - mcur) * L2E);
                    st[it][jt][r] = pv;
                    sum += pv;
                }
            sum += __shfl_xor(sum, 16, 64);
            sum += __shfl_xor(sum, 32, 64);
            li[it] += sum;
            // pack P as PV A-operand (kslot relabeling: jt-pair per frag)
            #pragma unroll
            for (int jp = 0; jp < 2; ++jp) {
                bf16x8 f;
                #pragma unroll
                for (int r = 0; r < 4; ++r) {
                    f[r]     = __bfloat16_as_short(__float2bfloat16(st[it][2*jp  ][r]));
                    f[r + 4] = __bfloat16_as_short(__float2bfloat16(st[it][2*jp+1][r]));
                }
                pb[it][jp] = f;
            }
        }

        // ---- PV: O[m=i][n=d]; B-frag = one b128 from swizzled V image.
        // Reads vt[tile&1]; in-flight DMA targets vt[(tile+1)&1] — disjoint.
        const int vr = (tile & 1) * (D*64);
        __builtin_amdgcn_s_setprio(1);
        #pragma unroll
        for (int dt = 0; dt < 8; ++dt) {
            const int vo = vr + (dt*16 + l16)*64;
            #pragma unroll
            for (int jp = 0; jp < 2; ++jp) {
                const bf16x8 bv = *(const bf16x8*)(&vt[vo + (((jp*4 + quad) ^ (l16 & 7)) * 8)]);
                #pragma unroll
                for (int it = 0; it < 2; ++it)
                    oacc[it][dt] = __builtin_amdgcn_mfma_f32_16x16x32_bf16(
                        pb[it][jp], bv, oacc[it][dt], 0, 0, 0);
            }
        }
        __builtin_amdgcn_s_setprio(0);
    }

    // ---- epilogue: NORMALIZED bf16 split-K partials (O/l), plus m & l
    __hip_bfloat16* op = opart + ((size_t)split * NN + q0 + wave*32) * D;
    #pragma unroll
    for (int it = 0; it < 2; ++it) {
        const float linv = 1.f / li[it];     // lane l16 holds row it*16+l16
        #pragma unroll
        for (int r = 0; r < 4; ++r) {
            const int m = it*16 + quad*4 + r;
            const float lr = __shfl(linv, quad*4 + r, 64);
            #pragma unroll
            for (int dt = 0; dt < 8; ++dt)
                op[(size_t)m*D + dt*16 + l16] = __float2bfloat16(oacc[it][dt][r] * lr);
        }
        if (quad == 0) {
            mpart[(size_t)split*NN + q0 + wave*32 + it*16 + l16] = mi[it];
            lpart[(size_t)split*NN + q0 + wave*32 + it*16 + l16] = li[it];
        }
    }
}

// ------------------------------------------------------------- combine ----
// out[q][d] = sum_s g_s * O'_s[q][d] / sum_s g_s,  g_s = l_s * 2^(m_s - m).
// One thread per 8 contiguous d of one q: bf16x8 loads, two f32x4 stores.
__global__ __launch_bounds__(256) void combine_kernel(
    const __hip_bfloat16* __restrict__ opart, const float* __restrict__ mpart,
    const float* __restrict__ lpart, float* __restrict__ out)
{
    const int idx = blockIdx.x * 256 + threadIdx.x;   // over 8192*16
    const int q  = idx >> 4;
    const int d8 = (idx & 15) * 8;
    float m = -1e30f;
    #pragma unroll
    for (int s = 0; s < KSPLIT; ++s) m = fmaxf(m, mpart[(size_t)s*NN + q]);
    float z = 0.f, o[8];
    #pragma unroll
    for (int e = 0; e < 8; ++e) o[e] = 0.f;
    #pragma unroll
    for (int s = 0; s < KSPLIT; ++s) {
        const float g = lpart[(size_t)s*NN + q] * exp2f((mpart[(size_t)s*NN + q] - m) * L2E);
        z += g;
        const u16x8 v = *(const u16x8*)(opart + ((size_t)s*NN + q)*D + d8);
        #pragma unroll
        for (int e = 0; e < 8; ++e)
            o[e] += g * __uint_as_float((unsigned)v[e] << 16);
    }
    const float zinv = 1.f / z;
    f32x4 lo, hi;
    #pragma unroll
    for (int e = 0; e < 4; ++e) { lo[e] = o[e] * zinv; hi[e] = o[e+4] * zinv; }
    *(f32x4*)(out + (size_t)q*D + d8)     = lo;
    *(f32x4*)(out + (size_t)q*D + d8 + 4) = hi;
}

// ---------------------------------------------------------------- launch --
extern "C" void kernel_launch(void* const* d_in, const int* in_sizes, int n_in,
                              void* d_out, int out_size, void* d_ws, size_t ws_size,
                              hipStream_t stream)
{
    // setup_inputs order: adjacency(0, UNUSED), node_features(1), W(2), b(3), attn_weights(4)
    const float* X = (const float*)d_in[1];
    const float* W = (const float*)d_in[2];
    const float* b = (const float*)d_in[3];
    const float* A = (const float*)d_in[4];
    float* out = (float*)d_out;

    char* ws = (char*)d_ws;
    __hip_bfloat16* h_hi = (__hip_bfloat16*)(ws);
    __hip_bfloat16* h_lo = (__hip_bfloat16*)(ws + (size_t)(2u  << 20));
    __hip_bfloat16* q_hi = (__hip_bfloat16*)(ws + (size_t)(4u  << 20));
    __hip_bfloat16* q_lo = (__hip_bfloat16*)(ws + (size_t)(6u  << 20));
    __hip_bfloat16* htp  = (__hip_bfloat16*)(ws + (size_t)(8u  << 20));
    __hip_bfloat16* opart = (__hip_bfloat16*)(ws + (size_t)(10u << 20));
    float* mpart = (float*)(ws + (size_t)(26u << 20));
    float* lpart = (float*)(ws + (size_t)(26u << 20) + (256u << 10));

    prep_kernel<<<NN/16, 256, 0, stream>>>(X, W, b, A, h_hi, h_lo, q_hi, q_lo, htp);
    flash_kernel<<<(NN/BQ) * KSPLIT, 256, 0, stream>>>(
        q_hi, q_lo, h_hi, h_lo, htp, opart, mpart, lpart);
    combine_kernel<<<(NN*16)/256, 256, 0, stream>>>(opart, mpart, lpart, out);
}